// Round 4
// baseline (110.528 us; speedup 1.0000x reference)
//
#include <hip/hip_runtime.h>
#include <math.h>

// Problem constants
constexpr int LL = 4096;
constexpr int CC = 256;
constexpr int MM = 32768;  // N*L rows

typedef unsigned int u32;
typedef unsigned short u16;
typedef __attribute__((ext_vector_type(8))) short bf16x8;
typedef __attribute__((ext_vector_type(4))) float f32x4;

__device__ __forceinline__ u16 f2b(float f) {
    u32 u = __float_as_uint(f);
    u32 r = (u + 0x7fffu + ((u >> 16) & 1u)) >> 16;
    return (u16)r;
}

// ---------------------------------------------------------------------------
// prep_w: bf16 transposed weights.
//   blocks 0..255:  Wt_in[n][k] = bf16(W_in[k][n]); Wt_out likewise
//   blocks 256..303: Wcomb[j][k] = bf16(j<24 ? W_off[k][j] : W_mask[k][j-24])
// ---------------------------------------------------------------------------
__global__ __launch_bounds__(256) void prep_w(
    const float* __restrict__ W_in, const float* __restrict__ W_out,
    const float* __restrict__ W_off, const float* __restrict__ W_mask,
    u16* __restrict__ Wt_in, u16* __restrict__ Wt_out, u16* __restrict__ Wcomb)
{
    const int b = blockIdx.x, t = threadIdx.x;
    if (b < 256) {
        Wt_in[b * 256 + t]  = f2b(W_in[t * 256 + b]);
        Wt_out[b * 256 + t] = f2b(W_out[t * 256 + b]);
    } else {
        const int j = b - 256;  // 0..47
        const float v = (j < 24) ? W_off[t * 24 + j] : W_mask[t * 24 + (j - 24)];
        Wcomb[j * 256 + t] = f2b(v);
    }
}

// ---------------------------------------------------------------------------
// gemm1: x_proj = x @ Wt_in^T + b_in (bf16 out). 32-row tiles, 1024 blocks.
// Wave w owns cols [w*64, w*64+64); 2 m-frags x 4 n-frags per wave.
// ---------------------------------------------------------------------------
__global__ __launch_bounds__(256) void gemm1(
    const float* __restrict__ x, const u16* __restrict__ Wt_in,
    const float* __restrict__ b_in, u16* __restrict__ xprojb)
{
    const int t = threadIdx.x;
    const int w = t >> 6, lane = t & 63;
    const int lr = lane & 15, lk8 = (lane >> 4) * 8;
    const int m0 = blockIdx.x * 32;

    f32x4 acc[2][4];
#pragma unroll
    for (int i = 0; i < 2; ++i)
#pragma unroll
        for (int j = 0; j < 4; ++j) acc[i][j] = f32x4{0.f, 0.f, 0.f, 0.f};

    const u16* Bw = Wt_in + (size_t)(w * 64) * 256;
#pragma unroll
    for (int ks = 0; ks < 8; ++ks) {
        const int ke = ks * 32 + lk8;
        bf16x8 af[2], bfr[4];
#pragma unroll
        for (int mt = 0; mt < 2; ++mt) {
            const float* ap = x + (size_t)(m0 + mt * 16 + lr) * 256 + ke;
            float4 f0 = *(const float4*)ap;
            float4 f1 = *(const float4*)(ap + 4);
            bf16x8 v;
            v[0] = (short)f2b(f0.x); v[1] = (short)f2b(f0.y);
            v[2] = (short)f2b(f0.z); v[3] = (short)f2b(f0.w);
            v[4] = (short)f2b(f1.x); v[5] = (short)f2b(f1.y);
            v[6] = (short)f2b(f1.z); v[7] = (short)f2b(f1.w);
            af[mt] = v;
        }
#pragma unroll
        for (int nt = 0; nt < 4; ++nt)
            bfr[nt] = *(const bf16x8*)(Bw + (size_t)(nt * 16 + lr) * 256 + ke);
#pragma unroll
        for (int mt = 0; mt < 2; ++mt)
#pragma unroll
            for (int nt = 0; nt < 4; ++nt)
                acc[mt][nt] = __builtin_amdgcn_mfma_f32_16x16x32_bf16(
                    af[mt], bfr[nt], acc[mt][nt], 0, 0, 0);
    }
    const int r0 = (lane >> 4) * 4;
#pragma unroll
    for (int nt = 0; nt < 4; ++nt) {
        const int cn = w * 64 + nt * 16 + lr;
        const float bv = b_in[cn];
#pragma unroll
        for (int mt = 0; mt < 2; ++mt)
#pragma unroll
            for (int r4 = 0; r4 < 4; ++r4)
                xprojb[(size_t)(m0 + mt * 16 + r0 + r4) * 256 + cn] =
                    f2b(acc[mt][nt][r4] + bv);
    }
}

// ---------------------------------------------------------------------------
// conv_ln_gelu: depthwise conv(K=3, zero pad) + LayerNorm(C) + exact GELU.
// One wave per (n,l) row; 4 channels per lane. fp32 math, bf16 output.
// High-occupancy standalone kernel (8192 blocks).
// ---------------------------------------------------------------------------
__global__ __launch_bounds__(256) void conv_ln_gelu(
    const float* __restrict__ x, const float* __restrict__ cw,
    const float* __restrict__ cbias, const float* __restrict__ lng,
    const float* __restrict__ lnb, u16* __restrict__ xf)
{
    const int wave = threadIdx.x >> 6;
    const int lane = threadIdx.x & 63;
    const int nl = (blockIdx.x << 2) + wave;
    const int l = nl & (LL - 1);
    const int c0 = lane << 2;
    const size_t base = (size_t)nl * CC + c0;

    float4 xc = *(const float4*)&x[base];
    float4 xm = make_float4(0.f, 0.f, 0.f, 0.f);
    float4 xp = make_float4(0.f, 0.f, 0.f, 0.f);
    if (l > 0)      xm = *(const float4*)&x[base - CC];
    if (l < LL - 1) xp = *(const float4*)&x[base + CC];

    float xmv[4] = {xm.x, xm.y, xm.z, xm.w};
    float xcv[4] = {xc.x, xc.y, xc.z, xc.w};
    float xpv[4] = {xp.x, xp.y, xp.z, xp.w};

    float y[4];
    float sum = 0.f, sq = 0.f;
#pragma unroll
    for (int j = 0; j < 4; ++j) {
        const int c = c0 + j;
        float v = fmaf(xmv[j], cw[c * 3 + 0],
                  fmaf(xcv[j], cw[c * 3 + 1],
                  fmaf(xpv[j], cw[c * 3 + 2], cbias[c])));
        y[j] = v;
        sum += v;
        sq  += v * v;
    }
#pragma unroll
    for (int off = 32; off > 0; off >>= 1) {
        sum += __shfl_xor(sum, off);
        sq  += __shfl_xor(sq, off);
    }
    const float mu  = sum * (1.f / CC);
    const float var = sq * (1.f / CC) - mu * mu;
    const float rs  = rsqrtf(var + 1e-6f);

    ushort4 o;
    float ov[4];
#pragma unroll
    for (int j = 0; j < 4; ++j) {
        const int c = c0 + j;
        const float tn = (y[j] - mu) * rs * lng[c] + lnb[c];
        ov[j] = 0.5f * tn * (1.f + erff(tn * 0.70710678118654752f));
    }
    o.x = f2b(ov[0]); o.y = f2b(ov[1]); o.z = f2b(ov[2]); o.w = f2b(ov[3]);
    *(ushort4*)&xf[base] = o;
}

// ---------------------------------------------------------------------------
// offmask_gemm: fused { offset/mask MFMA projection + softmax + bilinear
// gather -> LDS } + { final GEMM sampled@W_out + b_out -> fp32 out }.
// 32-row blocks (1024 blocks), 256 thr. LDS 28KB -> 4 blocks/CU resident.
// ---------------------------------------------------------------------------
__global__ __launch_bounds__(256) void offmask_gemm(
    const u16* __restrict__ xfeatb, const u16* __restrict__ xprojb,
    const u16* __restrict__ Wcomb, const float* __restrict__ boff,
    const float* __restrict__ bmask, const u16* __restrict__ Wt_out,
    const float* __restrict__ b_out, float* __restrict__ out)
{
    __shared__ __align__(16) char s_mem[16384];   // logit [32][50] f32, then
                                                  // sampled 32x256 bf16 (swz)
    __shared__ float4 s_pack[256 * 3];            // {a, b, i0bits, i1bits} 12KB
    float* logit = (float*)s_mem;

    const int t = threadIdx.x;
    const int w = t >> 6, lane = t & 63;
    const int lr = lane & 15, lk8 = (lane >> 4) * 8;
    const int r0 = (lane >> 4) * 4;
    const int blk = blockIdx.x;
    const size_t row0 = (size_t)blk * 32;

    // --- Phase 1: projection MFMA (waves 0,1: 16 rows x 48 cols each)
    if (w < 2) {
        f32x4 pacc[3];
#pragma unroll
        for (int ct = 0; ct < 3; ++ct) pacc[ct] = f32x4{0.f, 0.f, 0.f, 0.f};
        const u16* fbase = xfeatb + (row0 + w * 16 + lr) * 256;
#pragma unroll
        for (int ks = 0; ks < 8; ++ks) {
            const int ke = ks * 32 + lk8;
            bf16x8 a = *(const bf16x8*)(fbase + ke);
#pragma unroll
            for (int ct = 0; ct < 3; ++ct) {
                bf16x8 bfr = *(const bf16x8*)(Wcomb + (size_t)(ct * 16 + lr) * 256 + ke);
                pacc[ct] = __builtin_amdgcn_mfma_f32_16x16x32_bf16(a, bfr, pacc[ct], 0, 0, 0);
            }
        }
#pragma unroll
        for (int ct = 0; ct < 3; ++ct) {
            const int j = ct * 16 + lr;
            const float bj = (j < 24) ? boff[j] : bmask[j - 24];
#pragma unroll
            for (int r4 = 0; r4 < 4; ++r4)
                logit[(w * 16 + r0 + r4) * 50 + j] = pacc[ct][r4] + bj;
        }
    }
    __syncthreads();

    // --- Phase 2: softmax over K + locations (1 (row,g) pair per thread)
    {
        const int rw = t >> 3, g = t & 7;
        const float* lp = &logit[rw * 50];
        const float m0v = lp[24 + g * 3 + 0];
        const float m1v = lp[24 + g * 3 + 1];
        const float m2v = lp[24 + g * 3 + 2];
        const float mx = fmaxf(m0v, fmaxf(m1v, m2v));
        const float e0 = expf(m0v - mx), e1 = expf(m1v - mx), e2 = expf(m2v - mx);
        const float inv = 1.f / (e0 + e1 + e2);
        const float msk[3] = {e0 * inv, e1 * inv, e2 * inv};
        const float lf = (float)((blk & 127) * 32 + rw);
        float4 pk[3];
#pragma unroll
        for (int k = 0; k < 3; ++k) {
            const float loc = lf + (float)(k - 1) + lp[g * 3 + k];
            float r = fmodf(loc, (float)LL);
            if (r < 0.f) r += (float)LL;
            const float f0 = floorf(r);
            int i0 = (int)f0;
            i0 = i0 < 0 ? 0 : (i0 > LL - 1 ? LL - 1 : i0);
            const int i1 = i0 + 1;
            const float w1 = r - f0;
            const bool valid = (i1 < LL);
            pk[k] = make_float4(
                msk[k] * (1.f - w1),
                valid ? msk[k] * w1 : 0.f,
                __int_as_float(i0),
                __int_as_float(valid ? i1 : 0));
        }
        __syncthreads();   // logit reads done; s_mem reusable after this
#pragma unroll
        for (int k = 0; k < 3; ++k) s_pack[t * 3 + k] = pk[k];
    }
    __syncthreads();

    // --- Phase 3: gather-accumulate -> sampled bf16 tile in LDS (swizzled)
    {
        const int ihalf = t >> 7, tc = t & 127;
        const int c0 = tc * 2, g4 = tc >> 4;
        const u16* xpn = xprojb + (((size_t)(blk >> 7)) << 12) * 256;
        const int ibeg = ihalf * 16;
#pragma unroll 4
        for (int i = ibeg; i < ibeg + 16; ++i) {
            const int bidx = (i * 8 + g4) * 3;
            float ve = 0.f, vo = 0.f;
#pragma unroll
            for (int k = 0; k < 3; ++k) {
                const float4 pk = s_pack[bidx + k];
                const int i0 = __float_as_int(pk.z), i1 = __float_as_int(pk.w);
                const u32 u0 = *(const u32*)(xpn + (size_t)i0 * 256 + c0);
                const u32 u1 = *(const u32*)(xpn + (size_t)i1 * 256 + c0);
                ve = fmaf(pk.x, __uint_as_float(u0 << 16),
                     fmaf(pk.y, __uint_as_float(u1 << 16), ve));
                vo = fmaf(pk.x, __uint_as_float(u0 & 0xffff0000u),
                     fmaf(pk.y, __uint_as_float(u1 & 0xffff0000u), vo));
            }
            const u32 word = (u32)f2b(ve) | ((u32)f2b(vo) << 16);
            const int addr = (i * 512 + tc * 4) ^ ((i & 7) << 4);
            *(u32*)(s_mem + addr) = word;
        }
    }
    __syncthreads();

    // --- Phase 4: final GEMM 32x256 from LDS tile, wave w -> cols [w*64,+64)
    f32x4 acc[2][4];
#pragma unroll
    for (int i = 0; i < 2; ++i)
#pragma unroll
        for (int j = 0; j < 4; ++j) acc[i][j] = f32x4{0.f, 0.f, 0.f, 0.f};

    const u16* Bw = Wt_out + (size_t)(w * 64) * 256;
#pragma unroll
    for (int ks = 0; ks < 8; ++ks) {
        bf16x8 af[2], bfr[4];
#pragma unroll
        for (int mt = 0; mt < 2; ++mt) {
            const int rm = mt * 16 + lr;
            const int addr = (rm * 512 + ks * 64 + lk8 * 2) ^ ((rm & 7) << 4);
            af[mt] = *(const bf16x8*)(s_mem + addr);
        }
        const int ke = ks * 32 + lk8;
#pragma unroll
        for (int nt = 0; nt < 4; ++nt)
            bfr[nt] = *(const bf16x8*)(Bw + (size_t)(nt * 16 + lr) * 256 + ke);
#pragma unroll
        for (int mt = 0; mt < 2; ++mt)
#pragma unroll
            for (int nt = 0; nt < 4; ++nt)
                acc[mt][nt] = __builtin_amdgcn_mfma_f32_16x16x32_bf16(
                    af[mt], bfr[nt], acc[mt][nt], 0, 0, 0);
    }
#pragma unroll
    for (int nt = 0; nt < 4; ++nt) {
        const int cn = w * 64 + nt * 16 + lr;
        const float bv = b_out[cn];
#pragma unroll
        for (int mt = 0; mt < 2; ++mt)
#pragma unroll
            for (int r4 = 0; r4 < 4; ++r4)
                out[(row0 + mt * 16 + r0 + r4) * 256 + cn] = acc[mt][nt][r4] + bv;
    }
}

// ---------------------------------------------------------------------------
extern "C" void kernel_launch(void* const* d_in, const int* in_sizes, int n_in,
                              void* d_out, int out_size, void* d_ws, size_t ws_size,
                              hipStream_t stream)
{
    const float* x      = (const float*)d_in[0];
    const float* W_in   = (const float*)d_in[1];
    const float* b_in   = (const float*)d_in[2];
    const float* conv_w = (const float*)d_in[3];
    const float* conv_b = (const float*)d_in[4];
    const float* ln_g   = (const float*)d_in[5];
    const float* ln_b   = (const float*)d_in[6];
    const float* W_off  = (const float*)d_in[7];
    const float* b_off  = (const float*)d_in[8];
    const float* W_mask = (const float*)d_in[9];
    const float* b_mask = (const float*)d_in[10];
    const float* W_out  = (const float*)d_in[11];
    const float* b_out  = (const float*)d_in[12];

    // ws layout (~34 MB of the 256 MiB ws):
    //   [0, 16M)      x_feat bf16 [32768][256]
    //   [16M, 32M)    x_proj bf16 [32768][256]
    //   [32M, ...)    Wt_in (128K), Wt_out (128K), Wcomb (24K)
    u16* xfeatb = (u16*)d_ws;
    u16* xprojb = (u16*)((char*)d_ws + 16777216);
    char* wsb   = (char*)d_ws + 33554432;
    u16* Wt_in  = (u16*)(wsb);
    u16* Wt_out = (u16*)(wsb + 131072);
    u16* Wcombp = (u16*)(wsb + 262144);

    prep_w<<<304, 256, 0, stream>>>(W_in, W_out, W_off, W_mask, Wt_in, Wt_out, Wcombp);
    gemm1<<<MM / 32, 256, 0, stream>>>(x, Wt_in, b_in, xprojb);
    conv_ln_gelu<<<MM / 4, 256, 0, stream>>>(x, conv_w, conv_b, ln_g, ln_b, xfeatb);
    offmask_gemm<<<MM / 32, 256, 0, stream>>>(xfeatb, xprojb, Wcombp, b_off, b_mask,
                                              Wt_out, b_out, (float*)d_out);
}